// Round 18
// baseline (377.993 us; speedup 1.0000x reference)
//
#include <hip/hip_runtime.h>
#include <hip/hip_bf16.h>

typedef unsigned long long u64;

#define KNMS 1000      // MAX_BOX_PRE_NMS (hardcoded in reference)
#define KP   1024      // padded stride for per-pair arrays
#define CAP  4096      // candidate capacity per pair
#define NBIN 8192      // radix-select histogram bins (score bits >> 18)
#define SLICES 320     // k_selA: A-dim slices per batch
#define SCAP 32        // per (slice,class) key capacity (mean ~10, +7 sigma)
#define SLOTS (SLICES*SCAP)
#define CMAX 128       // fast-select supports C <= CMAX (else fallback path)
#define FSEL 1024      // k_fb compacted-candidate capacity
#define IOU_THR 0.5f

#define NEGINF __uint_as_float(0xFF800000u)

// ---------------------------------------------------------------------------
// helpers
// ---------------------------------------------------------------------------

__device__ __forceinline__ void find_cutoff(unsigned int* hist, int nbins,
    unsigned int* csum, int nthreads, int tid, unsigned int rank,
    unsigned int* s_bin, unsigned int* s_gt, unsigned int* s_total, int* s_all) {
  int chunk = nbins / nthreads;
  unsigned int cs = 0;
  int base = tid * chunk;
  for (int q = 0; q < chunk; q++) cs += hist[base + q];
  csum[tid] = cs;
  __syncthreads();
  if (tid == 0) {
    unsigned int total = 0;
    for (int ch = 0; ch < nthreads; ch++) total += csum[ch];
    *s_total = total;
    if (total <= rank) { *s_bin = 0u; *s_gt = 0u; *s_all = 1; }
    else {
      unsigned int acc = 0; int ch = nthreads - 1;
      while (acc + csum[ch] < rank) { acc += csum[ch]; ch--; }
      int bin = ch * chunk + chunk - 1;
      while (acc + hist[bin] < rank) { acc += hist[bin]; bin--; }
      *s_bin = (unsigned)bin; *s_gt = acc; *s_all = 0;
    }
  }
  __syncthreads();
}

template<int N, int NT>
__device__ __forceinline__ void bitonic_desc(u64* a, int tid) {
  for (int k = 2; k <= N; k <<= 1) {
    for (int j = k >> 1; j > 0; j >>= 1) {
      for (int t = tid; t < N; t += NT) {
        int ixj = t ^ j;
        if (ixj > t) {
          u64 x = a[t], y = a[ixj];
          if (((t & k) == 0) ? (x < y) : (x > y)) { a[t] = y; a[ixj] = x; }
        }
      }
      __syncthreads();
    }
  }
}

// Bit-exact greedy-NMS predicate vs reference, PURE f32 (Sterbenz argument,
// see round-6 notes): fl(I/U) > 0.5  <=>  (I+I) - U > U * 2^-24  in f32.
__device__ __forceinline__ bool iou_gt(float4 bi, float ai, float4 bj, float aj) {
  float ltx = fmaxf(bi.x, bj.x), lty = fmaxf(bi.y, bj.y);
  float rbx = fminf(bi.z, bj.z), rby = fminf(bi.w, bj.w);
  float ww = fmaxf(rbx - ltx, 0.f), hh = fmaxf(rby - lty, 0.f);
  float inter = ww * hh;
  float uni = (ai + aj) - inter;
  float q = (inter + inter) - uni;
  float t = uni * 0x1p-24f;
  return q > t;
}

// ---------------------------------------------------------------------------
// kernel S0: per batch, sample 4096 anchor-rows, build per-class 64-bin hists
// relative to thr's coarse bin, emit per-pair bit-cutoff AND a fused float
// GATE (see round-10 notes). Also zeroes gflag.
// ---------------------------------------------------------------------------
__global__ __launch_bounds__(1024) void k_sample(const float* __restrict__ cls,
    const float* __restrict__ thr_p, unsigned* __restrict__ gcut,
    float* __restrict__ gatef, unsigned* __restrict__ gflag, int A, int C) {
  int b = blockIdx.x, tid = threadIdx.x;
  __shared__ unsigned hist[CMAX * 64];
  float thr = *thr_p;
  unsigned base_bin = __float_as_uint(thr) >> 18;
  for (int i = tid; i < C * 64; i += 1024) hist[i] = 0u;
  __syncthreads();
  const float* src = cls + (size_t)b * A * C;
  const int NS = 4096;
  if ((C & 3) == 0) {
    int C4 = C >> 2;
    const float4* s4 = (const float4*)src;
    int tot4 = NS * C4;
    for (int idx = tid; idx < tot4; idx += 1024) {
      int s = idx / C4, c4 = idx - s * C4;
      int a = (int)(((long long)s * A) >> 12);
      float4 v = s4[(size_t)a * C4 + c4];
      float vv[4] = {v.x, v.y, v.z, v.w};
#pragma unroll
      for (int q = 0; q < 4; q++) {
        float sv = vv[q];
        if (sv > thr) {
          unsigned rel = (__float_as_uint(sv) >> 18) - base_bin;
          if (rel > 63u) rel = 63u;
          atomicAdd(&hist[(c4 * 4 + q) * 64 + rel], 1u);
        }
      }
    }
  } else {
    int tot = NS * C;
    for (int idx = tid; idx < tot; idx += 1024) {
      int s = idx / C, c = idx - s * C;
      int a = (int)(((long long)s * A) >> 12);
      float sv = src[(size_t)a * C + c];
      if (sv > thr) {
        unsigned rel = (__float_as_uint(sv) >> 18) - base_bin;
        if (rel > 63u) rel = 63u;
        atomicAdd(&hist[c * 64 + rel], 1u);
      }
    }
  }
  __syncthreads();
  if (tid < C) {
    int ns = NS < A ? NS : A;
    long long r = (1500LL * ns) / A; if (r < 1) r = 1;
    unsigned acc = 0; int bin = -1;
    for (int rb = 63; rb >= 0; --rb) {
      acc += hist[tid * 64 + rb];
      if (acc >= (unsigned)r) { bin = rb; break; }
    }
    unsigned cutv = (bin < 0) ? 0u : (base_bin + (unsigned)bin);
    gcut[b * C + tid] = cutv;
    float gate = thr;
    if (cutv != 0u) {
      unsigned cb = cutv << 18;
      if (__uint_as_float(cb) > thr) gate = __uint_as_float(cb - 1u);
    }
    gatef[b * C + tid] = gate;
    gflag[b * C + tid] = 0u;
  }
}

// ---------------------------------------------------------------------------
// kernel S1 (vec, C%4==0): divide-free streaming compact (round-10 version).
// ---------------------------------------------------------------------------
__global__ void k_selA(const float* __restrict__ cls,
    const float* __restrict__ gatef, u64* __restrict__ gcand,
    unsigned* __restrict__ gpc, unsigned* __restrict__ gflag, int A, int C) {
  int slice = blockIdx.x, b = blockIdx.y, tid = threadIdx.x;
  int nt = blockDim.x;
  __shared__ u64 stage[CMAX * SCAP];
  __shared__ unsigned pcnt[CMAX];
  int C4 = C >> 2;
  for (int i = tid; i < C; i += nt) pcnt[i] = 0u;
  __syncthreads();
  int ANC = (A + SLICES - 1) / SLICES;
  int a0 = slice * ANC, a1 = min(A, a0 + ANC);
  int c4 = tid % C4;
  int r0 = tid / C4;
  int R = nt / C4;
  float4 g4 = ((const float4*)(gatef + (size_t)b * C))[c4];
  const float4* p = (const float4*)cls + (size_t)b * A * C4
                    + (size_t)(a0 + r0) * C4 + c4;
  int cb = c4 << 2;
  for (int ar = a0 + r0; ar < a1; ar += R, p += (size_t)R * C4) {
    float4 v = *p;
    bool p0 = v.x > g4.x, p1 = v.y > g4.y, p2 = v.z > g4.z, p3 = v.w > g4.w;
    if (p0 | p1 | p2 | p3) {
      unsigned ia = (unsigned)(~(unsigned)ar);
      if (p0) { unsigned pos = atomicAdd(&pcnt[cb + 0], 1u);
        if (pos < SCAP) stage[(cb + 0) * SCAP + pos] = ((u64)__float_as_uint(v.x) << 32) | ia; }
      if (p1) { unsigned pos = atomicAdd(&pcnt[cb + 1], 1u);
        if (pos < SCAP) stage[(cb + 1) * SCAP + pos] = ((u64)__float_as_uint(v.y) << 32) | ia; }
      if (p2) { unsigned pos = atomicAdd(&pcnt[cb + 2], 1u);
        if (pos < SCAP) stage[(cb + 2) * SCAP + pos] = ((u64)__float_as_uint(v.z) << 32) | ia; }
      if (p3) { unsigned pos = atomicAdd(&pcnt[cb + 3], 1u);
        if (pos < SCAP) stage[(cb + 3) * SCAP + pos] = ((u64)__float_as_uint(v.w) << 32) | ia; }
    }
  }
  __syncthreads();
  for (int idx = tid; idx < C * SCAP; idx += nt) {
    int c = idx >> 5, j = idx & (SCAP - 1);
    unsigned cnt2 = pcnt[c]; if (cnt2 > SCAP) cnt2 = SCAP;
    if ((unsigned)j < cnt2)
      gcand[(size_t)(b * C + c) * SLOTS + slice * SCAP + j] = stage[idx];
  }
  for (int c = tid; c < C; c += nt) {
    unsigned cnt2 = pcnt[c];
    if (cnt2 > SCAP) { atomicOr(&gflag[b * C + c], 1u); cnt2 = SCAP; }
    gpc[(size_t)(b * C + c) * SLICES + slice] = cnt2;
  }
}

// Scalar variant for C % 4 != 0.
__global__ void k_selAs(const float* __restrict__ cls,
    const float* __restrict__ gatef, u64* __restrict__ gcand,
    unsigned* __restrict__ gpc, unsigned* __restrict__ gflag, int A, int C) {
  int slice = blockIdx.x, b = blockIdx.y, tid = threadIdx.x;
  int nt = blockDim.x;
  __shared__ u64 stage[CMAX * SCAP];
  __shared__ unsigned pcnt[CMAX];
  for (int i = tid; i < C; i += nt) pcnt[i] = 0u;
  __syncthreads();
  int ANC = (A + SLICES - 1) / SLICES;
  int a0 = slice * ANC, a1 = min(A, a0 + ANC);
  int c = tid % C;
  int r0 = tid / C;
  int R = nt / C;
  float gate = gatef[(size_t)b * C + c];
  const float* p = cls + (size_t)b * A * C + (size_t)(a0 + r0) * C + c;
  for (int ar = a0 + r0; ar < a1; ar += R, p += (size_t)R * C) {
    float sv = *p;
    if (sv > gate) {
      unsigned pos = atomicAdd(&pcnt[c], 1u);
      if (pos < SCAP)
        stage[c * SCAP + pos] = ((u64)__float_as_uint(sv) << 32) | (unsigned)(~(unsigned)ar);
    }
  }
  __syncthreads();
  for (int idx = tid; idx < C * SCAP; idx += nt) {
    int cc = idx >> 5, j = idx & (SCAP - 1);
    unsigned cnt2 = pcnt[cc]; if (cnt2 > SCAP) cnt2 = SCAP;
    if ((unsigned)j < cnt2)
      gcand[(size_t)(b * C + cc) * SLOTS + slice * SCAP + j] = stage[idx];
  }
  for (int cc = tid; cc < C; cc += nt) {
    unsigned cnt2 = pcnt[cc];
    if (cnt2 > SCAP) { atomicOr(&gflag[b * C + cc], 1u); cnt2 = SCAP; }
    gpc[(size_t)(b * C + cc) * SLICES + slice] = cnt2;
  }
}

// ---------------------------------------------------------------------------
// kernel S2: per pair: scan slice counts, gather keys, radix-select the top
// <=1024 (64-bin coarse hist + optional 2048-bin refine) + bitonic-1024;
// full bitonic-4096 fallback for wide-range / tie-overflow / bad capture.
// (round-17 version, measured ~65us by delta-accounting)
// ---------------------------------------------------------------------------
__global__ __launch_bounds__(1024) void k_selB(const u64* __restrict__ gcand,
    const unsigned* __restrict__ gpc, const unsigned* __restrict__ gcut,
    const unsigned* __restrict__ gflag, const float* __restrict__ gatef,
    const float* __restrict__ cls, const float* __restrict__ thr_p,
    const float* __restrict__ tanch,
    float* __restrict__ scores_s, float* __restrict__ boxes_s,
    int* __restrict__ cnt_s, int A, int C) {
  int pair = blockIdx.x, tid = threadIdx.x;
  int b = pair / C, c = pair - b * C;
  __shared__ union { unsigned hist[NBIN]; u64 cand[CAP]; } sh;  // 32KB
  __shared__ u64 cand2[1024];                                   // 8KB
  __shared__ unsigned h2[2048];                                 // 8KB
  __shared__ unsigned hw[16][64];                               // 4KB
  __shared__ unsigned hist64[64];
  __shared__ unsigned cnts[SLICES];
  __shared__ unsigned pre[SLICES];
  __shared__ unsigned csum[1024];
  __shared__ unsigned s_b1, s_gt, s_tot, s_b2, s_gt2, s_tot2;
  __shared__ int s_all, s_all2, s_ovf, s_mode, s_lvl2, s_wide, s_ntake;

  unsigned flag = gflag[pair];
  for (int i = tid; i < SLICES; i += 1024) {
    unsigned v = gpc[(size_t)pair * SLICES + i];
    cnts[i] = v; pre[i] = v;
  }
  __syncthreads();
  for (int d = 1; d < SLICES; d <<= 1) {
    unsigned v = 0;
    if (tid < SLICES && tid >= d) v = pre[tid - d];
    __syncthreads();
    if (tid < SLICES && tid >= d) pre[tid] += v;
    __syncthreads();
  }
  unsigned total = pre[SLICES - 1];
  bool mode_sampled = (gcut[pair] != 0u);
  bool bad = (flag != 0u) || (total > CAP) ||
             (mode_sampled && total < (unsigned)KNMS);
  unsigned n_valid_u;
  bool fullsort;
  if (!bad) {
    for (int t = tid; t < CAP; t += 1024) sh.cand[t] = 0ull;
    __syncthreads();
    const u64* src = gcand + (size_t)pair * SLOTS;
    for (int idx = tid; idx < SLOTS; idx += 1024) {
      int s = idx >> 5, j = idx & (SCAP - 1);
      if ((unsigned)j < cnts[s]) sh.cand[(pre[s] - cnts[s]) + j] = src[idx];
    }
    n_valid_u = total < (unsigned)KNMS ? total : (unsigned)KNMS;
    // ---- radix-select top <=1024 ----
    unsigned base = __float_as_uint(gatef[pair]) >> 18;
    for (int i = tid; i < 16 * 64; i += 1024) (&hw[0][0])[i] = 0u;
    if (tid == 0) { s_wide = 0; s_ntake = 0; }
    __syncthreads();
    int wv = tid >> 6;
    for (int t = tid; t < CAP; t += 1024) {
      u64 key = sh.cand[t];
      if (!key) continue;
      unsigned rel = ((unsigned)(key >> 32) >> 18) - base;
      if (rel > 63u) s_wide = 1;
      else atomicAdd(&hw[wv][rel], 1u);
    }
    __syncthreads();
    if (tid < 64) {
      unsigned s = 0;
#pragma unroll
      for (int w = 0; w < 16; w++) s += hw[w][tid];
      hist64[tid] = s;
    }
    __syncthreads();
    if (tid == 0) {
      int mode = 0; unsigned b1 = 0, gt = 0; int lvl2 = 0;
      if (s_wide) mode = 2;
      else if (total > (unsigned)KNMS) {
        unsigned acc = 0; int bin = 63;
        for (; bin > 0; --bin) {
          unsigned h = hist64[bin];
          if (acc + h >= (unsigned)KNMS) break;
          acc += h;
        }
        b1 = (unsigned)bin; gt = acc;
        if (gt + hist64[b1] > 1024u) lvl2 = 1;
      }
      s_b1 = b1; s_gt = gt; s_mode = mode; s_lvl2 = lvl2;
    }
    __syncthreads();
    unsigned b1v = s_b1, gtv = s_gt;
    int lvl2 = s_lvl2;
    unsigned b2v = 0;
    if (s_mode == 0 && lvl2) {
      for (int i = tid; i < 2048; i += 1024) h2[i] = 0u;
      __syncthreads();
      for (int t = tid; t < CAP; t += 1024) {
        u64 key = sh.cand[t];
        if (!key) continue;
        unsigned bits = (unsigned)(key >> 32);
        if (((bits >> 18) - base) == b1v)
          atomicAdd(&h2[(bits >> 7) & 2047u], 1u);
      }
      __syncthreads();
      find_cutoff(h2, 2048, csum, 1024, tid, (unsigned)KNMS - gtv,
                  &s_b2, &s_gt2, &s_tot2, &s_all2);
      if (tid == 0) {
        if (s_all2 || gtv + s_gt2 + h2[s_b2] > 1024u) s_mode = 2; // paranoid
      }
      __syncthreads();
      b2v = s_all2 ? 0u : s_b2;
    }
    fullsort = (s_mode == 2);
    if (!fullsort) {
      if (tid < 1024) cand2[tid] = 0ull;
      __syncthreads();
      for (int t = tid; t < CAP; t += 1024) {
        u64 key = sh.cand[t];
        if (!key) continue;
        unsigned bits = (unsigned)(key >> 32);
        unsigned rel = (bits >> 18) - base;
        bool take = rel > b1v ||
                    (rel == b1v && (!lvl2 || ((bits >> 7) & 2047u) >= b2v));
        if (take) {
          int pos = atomicAdd(&s_ntake, 1);
          if (pos < 1024) cand2[pos] = key;
        }
      }
      __syncthreads();
    }
  } else {
    // ---- exact fallback (strided reads; rare) ----
    fullsort = true;
    const float* col = cls + (size_t)b * A * C + c;
    float thr = *thr_p;
    for (int i = tid; i < NBIN; i += 1024) sh.hist[i] = 0u;
    __syncthreads();
    for (int a = tid; a < A; a += 1024) {
      float sv = col[(size_t)a * C];
      if (sv > thr) atomicAdd(&sh.hist[__float_as_uint(sv) >> 18], 1u);
    }
    __syncthreads();
    find_cutoff(sh.hist, NBIN, csum, 1024, tid, KNMS, &s_b1, &s_gt, &s_tot, &s_all);
    unsigned b1 = s_all ? 0u : s_b1;
    unsigned tot = s_tot;
    __syncthreads();
    for (int t = tid; t < CAP; t += 1024) sh.cand[t] = 0ull;
    if (tid == 0) s_ovf = 0;
    __syncthreads();
    int lane = tid & 63, wv = tid >> 6;     // 16 waves, SEG=240, OVF=256
    u64* seg = sh.cand + wv * 240;
    int nloc = 0;
    u64 lmask = (1ull << lane) - 1ull;
    for (int a = tid; a < A; a += 1024) {
      float sv = col[(size_t)a * C];
      unsigned bits = __float_as_uint(sv);
      bool take = (sv > thr) && ((bits >> 18) >= b1);
      u64 m = __ballot(take);
      if (m) {
        if (take) {
          u64 key = ((u64)bits << 32) | (unsigned)(~(unsigned)a);
          int pos = nloc + (int)__popcll(m & lmask);
          if (pos < 240) seg[pos] = key;
          else { int p2 = atomicAdd(&s_ovf, 1); if (p2 < 256) sh.cand[16 * 240 + p2] = key; }
        }
        nloc += (int)__popcll(m);
      }
    }
    __syncthreads();
    n_valid_u = tot < (unsigned)KNMS ? tot : (unsigned)KNMS;
  }

  if (fullsort) bitonic_desc<CAP, 1024>(sh.cand, tid);
  else          bitonic_desc<1024, 1024>(cand2, tid);
  const u64* osrc = fullsort ? (const u64*)sh.cand : (const u64*)cand2;

  int n_valid = (int)n_valid_u;
  for (int k = tid; k < KNMS; k += 1024) {
    u64 key = osrc[k];
    float sc; float4 bx;
    if (k < n_valid && key != 0ull) {
      sc = __uint_as_float((unsigned)(key >> 32));
      unsigned a = ~(unsigned)key;
      bx = ((const float4*)tanch)[(size_t)b * A + a];
    } else {
      sc = NEGINF; bx = make_float4(0.f, 0.f, 0.f, 0.f);
    }
    scores_s[(size_t)pair * KP + k] = sc;
    ((float4*)boxes_s)[(size_t)pair * KP + k] = bx;
  }
  if (tid == 0) cnt_s[pair] = n_valid;
}

// ---------------------------------------------------------------------------
// kernel 3: suppressor-COLUMN matrix colm[pair][wi][j] (round-14 internals).
// Round-18: split into TWO DISTINCTLY-NAMED kernels (k_iouA/k_iouB, koff 0/1)
// so each half (~57us) sits BELOW the 60-110us hidden suspects and the
// rocprof top-5 (which fills with clones of the single slowest kernel) must
// reveal the true #2. Same balanced {Ac=g, Bc=15-g} decomposition (r16-
// validated, absmax 0).
// ---------------------------------------------------------------------------
__device__ __forceinline__ void iou_body(const float* __restrict__ boxes_s,
    const int* __restrict__ cnt_s, u64* __restrict__ mat, int koff) {
  int pair = blockIdx.x;
  int g = (int)(blockIdx.y << 1) + koff;   // g in [0,8)
  int Ac = g, Bc = 15 - g;
  int cnt = cnt_s[pair];
  __shared__ float4 sbox[KNMS];
  __shared__ u64 rowm[2][KP];
  for (int i = threadIdx.x; i < KNMS; i += 256)
    sbox[i] = ((const float4*)boxes_s)[(size_t)pair * KP + i];
  {
    u64* rz = &rowm[0][0];
    for (int i = threadIdx.x; i < 2 * KP; i += 256) rz[i] = 0ull;
  }
  __syncthreads();
  int lane = threadIdx.x & 63;
  int wv = __builtin_amdgcn_readfirstlane(threadIdx.x >> 6);
  float4 z4 = make_float4(0.f, 0.f, 0.f, 0.f);
  float4 biA = sbox[Ac * 64 + lane];
  int ib = Bc * 64 + lane;
  float4 biB = (ib < KNMS) ? sbox[ib] : z4;
  float aiA = (biA.z - biA.x) * (biA.w - biA.y);
  float aiB = (biB.z - biB.x) * (biB.w - biB.y);
  int lim = cnt;
  // seg1: j in (Ac*64, Ac*64+64): A masked (lanes < j-Ac*64)
  int e1 = Ac * 64 + 64; if (e1 > lim) e1 = lim;
  for (int j = Ac * 64 + 1 + wv; j < e1; j += 4) {
    float4 bj = sbox[j];
    float aj = (bj.z - bj.x) * (bj.w - bj.y);
    u64 mk = (1ull << (j - Ac * 64)) - 1ull;
    u64 w0 = __ballot(iou_gt(biA, aiA, bj, aj)) & mk;
    if (lane == 0) rowm[0][j] = w0;
  }
  // seg2: j in [Ac*64+64, Bc*64]: A plain (unroll-2 per wave)
  int s2e = Bc * 64 + 1; if (s2e > lim) s2e = lim;
  for (int j = Ac * 64 + 64 + (wv << 1); j < s2e; j += 8) {
    float4 bj0 = sbox[j];
    bool h2b = (j + 1 < s2e);
    float4 bj1 = h2b ? sbox[j + 1] : z4;
    float aj0 = (bj0.z - bj0.x) * (bj0.w - bj0.y);
    float aj1 = (bj1.z - bj1.x) * (bj1.w - bj1.y);
    u64 w00 = __ballot(iou_gt(biA, aiA, bj0, aj0));
    u64 w01 = __ballot(iou_gt(biA, aiA, bj1, aj1));
    if (lane == 0) { rowm[0][j] = w00; if (h2b) rowm[0][j + 1] = w01; }
  }
  // seg3: j in (Bc*64, Bc*64+64): A plain + B masked
  int e3 = Bc * 64 + 64; if (e3 > lim) e3 = lim;
  for (int j = Bc * 64 + 1 + wv; j < e3; j += 4) {
    float4 bj = sbox[j];
    float aj = (bj.z - bj.x) * (bj.w - bj.y);
    u64 w0 = __ballot(iou_gt(biA, aiA, bj, aj));
    u64 mk = (1ull << (j - Bc * 64)) - 1ull;
    u64 w1 = __ballot(iou_gt(biB, aiB, bj, aj)) & mk;
    if (lane == 0) { rowm[0][j] = w0; rowm[1][j] = w1; }
  }
  // seg4: j in [Bc*64+64, lim): A plain + B plain (unroll-2 per wave)
  for (int j = Bc * 64 + 64 + (wv << 1); j < lim; j += 8) {
    float4 bj0 = sbox[j];
    bool h2b = (j + 1 < lim);
    float4 bj1 = h2b ? sbox[j + 1] : z4;
    float aj0 = (bj0.z - bj0.x) * (bj0.w - bj0.y);
    float aj1 = (bj1.z - bj1.x) * (bj1.w - bj1.y);
    u64 w00 = __ballot(iou_gt(biA, aiA, bj0, aj0));
    u64 w10 = __ballot(iou_gt(biB, aiB, bj0, aj0));
    u64 w01 = __ballot(iou_gt(biA, aiA, bj1, aj1));
    u64 w11 = __ballot(iou_gt(biB, aiB, bj1, aj1));
    if (lane == 0) {
      rowm[0][j] = w00; rowm[1][j] = w10;
      if (h2b) { rowm[0][j + 1] = w01; rowm[1][j + 1] = w11; }
    }
  }
  __syncthreads();
  {
    u64* dstA = mat + ((size_t)pair * 16 + Ac) * KP;
    for (int t = Ac * 64 + threadIdx.x; t < cnt; t += 256) dstA[t] = rowm[0][t];
    u64* dstB = mat + ((size_t)pair * 16 + Bc) * KP;
    for (int t = Bc * 64 + threadIdx.x; t < cnt; t += 256) dstB[t] = rowm[1][t];
  }
}

__global__ __launch_bounds__(256) void k_iouA(const float* __restrict__ boxes_s,
    const int* __restrict__ cnt_s, u64* __restrict__ mat) {
  iou_body(boxes_s, cnt_s, mat, 0);
}
__global__ __launch_bounds__(256) void k_iouB(const float* __restrict__ boxes_s,
    const int* __restrict__ cnt_s, u64* __restrict__ mat) {
  iou_body(boxes_s, cnt_s, mat, 1);
}

// ---------------------------------------------------------------------------
// kernel 4 (scan+fa, colm orientation; round-14 version): 1 wave per pair.
// key = (score_bits << 32) | ~(c*KNMS + k)
// ---------------------------------------------------------------------------
__global__ __launch_bounds__(64) void k_scanfa(const u64* __restrict__ mat,
    const int* __restrict__ cnt_s, const float* __restrict__ scores_s,
    u64* __restrict__ fa, int C, int mb) {
  int pair = blockIdx.x;
  int l = threadIdx.x;
  int cnt = cnt_s[pair];
  const u64* cm = mat + (size_t)pair * KP * 16;
  u64 supw = 0ull;
  u64 kfin = 0ull;
  for (int t = 0; t < 16; t++) {
    int base = t * 64;
    if (base >= cnt) break;
    int nb = cnt - base; if (nb > 64) nb = 64;
    u64 validt = (nb >= 64) ? ~0ull : ((1ull << nb) - 1ull);
    const u64* cmt = cm + (size_t)t * KP;
    u64 dg = cmt[base + l];
    u64 v[15];
#pragma unroll
    for (int q = 0; q < 15; q++) {
      int jw = t + 1 + q;
      v[q] = (jw < 16 && jw * 64 < cnt) ? cmt[jw * 64 + l] : 0ull;
    }
    u64 supt = __shfl(supw, t);
    u64 rem = validt & ~supt;
    u64 nz = __ballot(dg != 0ull) & rem;
    u64 keep = rem & ~nz;
    while (nz) {
      int i = __ffsll((long long)nz) - 1;
      nz &= nz - 1;
      u64 di = __shfl(dg, i);
      if ((di & keep) == 0ull) keep |= 1ull << i;
    }
    if (l == t) kfin = keep;
#pragma unroll
    for (int q = 0; q < 15; q++) {
      int jw = t + 1 + q;
      if (jw < 16) {
        u64 bal = __ballot((v[q] & keep) != 0ull);
        if (l == jw) supw |= bal;
      }
    }
  }
  int c = pair % C;
  int pc = __popcll(kfin);
  int scan = pc;
  for (int d = 1; d < 16; d <<= 1) {
    int o = __shfl_up(scan, d);
    if (l >= d) scan += o;
  }
  int basep = scan - pc;
  int total = __shfl(scan, 15);
  if (l < 16) {
    u64 mm = kfin; int r = basep;
    while (mm && r < mb) {
      int bit = __ffsll((long long)mm) - 1; mm &= mm - 1;
      int k = l * 64 + bit;
      float s = scores_s[(size_t)pair * KP + k];
      fa[(size_t)pair * mb + r] =
          ((u64)__float_as_uint(s) << 32) | (unsigned)(~(unsigned)(c * KNMS + k));
      r++;
    }
  }
  int start = total < mb ? total : mb;
  for (int r = start + l; r < mb; r += 64) fa[(size_t)pair * mb + r] = 0ull;
}

// ---------------------------------------------------------------------------
// kernel 5b: per batch: top-mb of C*mb keys via 2-level radix select +
// 1024-key bitonic.
// ---------------------------------------------------------------------------
__global__ __launch_bounds__(1024) void k_fb(const u64* __restrict__ fa,
    const float* __restrict__ boxes_s, float* __restrict__ out,
    int B, int C, int mb) {
  int b = blockIdx.x, tid = threadIdx.x;
  __shared__ union { unsigned int hist[NBIN]; u64 cand[FSEL]; } sh;
  __shared__ unsigned int csum[1024];
  __shared__ unsigned int s_b1, s_gt, s_tot, s_b2, s_gt2, s_tot2;
  __shared__ int s_all, s_all2, s_n, s_lvl2;
  int nk = C * mb;
  const u64* src = fa + (size_t)b * nk;

  for (int i = tid; i < NBIN; i += 1024) sh.hist[i] = 0u;
  __syncthreads();
  for (int i = tid; i < nk; i += 1024) {
    u64 key = src[i];
    if (key) atomicAdd(&sh.hist[(unsigned)(key >> 32) >> 18], 1u);
  }
  __syncthreads();
  find_cutoff(sh.hist, NBIN, csum, 1024, tid, (unsigned)mb, &s_b1, &s_gt, &s_tot, &s_all);
  unsigned b1 = s_all ? 0u : s_b1;
  unsigned gt1 = s_gt, tot = s_tot;
  int all1 = s_all;
  unsigned m1 = sh.hist[b1];
  if (tid == 0) s_lvl2 = (!all1 && gt1 + m1 > FSEL) ? 1 : 0;
  __syncthreads();
  int lvl2 = s_lvl2;
  unsigned b2 = 0; int all2 = 1;
  if (lvl2) {
    for (int i = tid; i < 2048; i += 1024) sh.hist[i] = 0u;
    __syncthreads();
    for (int i = tid; i < nk; i += 1024) {
      u64 key = src[i];
      if (key) {
        unsigned bits = (unsigned)(key >> 32);
        if ((bits >> 18) == b1) atomicAdd(&sh.hist[(bits >> 7) & 2047u], 1u);
      }
    }
    __syncthreads();
    find_cutoff(sh.hist, 2048, csum, 1024, tid, (unsigned)mb - gt1,
                &s_b2, &s_gt2, &s_tot2, &s_all2);
    all2 = s_all2;
    b2 = all2 ? 0u : s_b2;
  }
  for (int t = tid; t < FSEL; t += 1024) sh.cand[t] = 0ull;
  if (tid == 0) s_n = 0;
  __syncthreads();
  for (int i = tid; i < nk; i += 1024) {
    u64 key = src[i];
    if (!key) continue;
    unsigned bits = (unsigned)(key >> 32);
    unsigned bin = bits >> 18;
    bool take = all1 || bin > b1 ||
                (bin == b1 && (!lvl2 || all2 || ((bits >> 7) & 2047u) >= b2));
    if (take) {
      int pos = atomicAdd(&s_n, 1);
      if (pos < FSEL) sh.cand[pos] = key;
    }
  }
  __syncthreads();
  bitonic_desc<FSEL, 1024>(sh.cand, tid);

  int n_out = (int)tot < mb ? (int)tot : mb;
  for (int k = tid; k < mb; k += 1024) {
    u64 key = sh.cand[k];
    float4 bx = make_float4(0.f, 0.f, 0.f, 0.f);
    float sc = 0.f, cf = -1.f;
    if (k < n_out && key != 0ull) {
      sc = __uint_as_float((unsigned)(key >> 32));
      unsigned flat = ~(unsigned)key;
      int c = flat / KNMS;
      int kk = flat - c * KNMS;
      bx = ((const float4*)boxes_s)[(size_t)(b * C + c) * KP + kk];
      cf = (float)c;
    }
    size_t ro = (size_t)(b * mb + k) * 4;
    out[ro + 0] = bx.x; out[ro + 1] = bx.y; out[ro + 2] = bx.z; out[ro + 3] = bx.w;
    out[(size_t)B * mb * 4 + b * mb + k] = sc;
    out[(size_t)B * mb * 5 + b * mb + k] = cf;
  }
}

// ---------------------------------------------------------------------------
extern "C" void kernel_launch(void* const* d_in, const int* in_sizes, int n_in,
                              void* d_out, int out_size, void* d_ws, size_t ws_size,
                              hipStream_t stream) {
  const float* classification = (const float*)d_in[3];
  const float* tanch = (const float*)d_in[4];
  const float* thr_p = (const float*)d_in[5];

  int B = in_sizes[0] / (3 * 64 * 64);
  if (B <= 0) B = 4;
  long long BA = (long long)in_sizes[4] / 4;
  int A = (int)(BA / B);
  int C = (int)((long long)in_sizes[3] / BA);
  int NP = B * C;
  int mb = out_size / (B * 6);

  auto rsz = [](size_t x) { return (x + 255) & ~(size_t)255; };
  size_t off = 0;
  auto take = [&](size_t bytes) {
    void* p = (char*)d_ws + off;
    off += rsz(bytes);
    return p;
  };
  float* scores_s = (float*)take((size_t)NP * KP * 4);
  float* boxes_s  = (float*)take((size_t)NP * KP * 16);
  float* area_s   = (float*)take((size_t)NP * KP * 4);   // only used as fa
  int*   cnt_s    = (int*)take((size_t)NP * 4);
  u64*   mat      = (u64*)take((size_t)NP * KP * 16 * 8);  // 41.9 MB (colm)

  // Aliases (disjoint lifetimes):
  //   gcand/gpc/gcut/gflag/gatef live k_sample..k_selB (before k_iou writes
  //   mat); fa aliases area_s (unused elsewhere; k_scanfa reads mat, so fa
  //   must not alias mat).
  char* matc = (char*)mat;
  size_t ao = 0;
  u64* gcand      = (u64*)(matc + ao);      ao += rsz((size_t)NP * SLOTS * 8);   // 26.2 MB
  unsigned* gpc   = (unsigned*)(matc + ao); ao += rsz((size_t)NP * SLICES * 4);  // 0.41 MB
  unsigned* gcut  = (unsigned*)(matc + ao); ao += rsz((size_t)NP * 4);
  unsigned* gflag = (unsigned*)(matc + ao); ao += rsz((size_t)NP * 4);
  float* gatef    = (float*)(matc + ao);    ao += rsz((size_t)NP * 4);
  u64* fa = (u64*)area_s;   // NP*mb*8 = 256 KB <= NP*KP*4 = 1.31 MB

  int fastsel = (C <= CMAX) ? 1 : 0;

  if (fastsel) {
    k_sample<<<B, 1024, 0, stream>>>(classification, thr_p, gcut, gatef, gflag, A, C);
    if ((C & 3) == 0) {
      int C4 = C >> 2;
      int R = 512 / C4; if (R < 1) R = 1;
      k_selA<<<dim3(SLICES, B), C4 * R, 0, stream>>>(classification, gatef,
                                                     gcand, gpc, gflag, A, C);
    } else {
      int R = 512 / C; if (R < 1) R = 1;
      k_selAs<<<dim3(SLICES, B), C * R, 0, stream>>>(classification, gatef,
                                                     gcand, gpc, gflag, A, C);
    }
  } else {
    hipMemsetAsync(gflag, 1, (size_t)NP * 4, stream);
    hipMemsetAsync(gcut, 0, (size_t)NP * 4, stream);
    hipMemsetAsync(gatef, 0, (size_t)NP * 4, stream);
  }
  k_selB<<<NP, 1024, 0, stream>>>(gcand, gpc, gcut, gflag, gatef, classification,
                                  thr_p, tanch, scores_s, boxes_s, cnt_s, A, C);
  k_iouA<<<dim3(NP, 4), 256, 0, stream>>>(boxes_s, cnt_s, mat);
  k_iouB<<<dim3(NP, 4), 256, 0, stream>>>(boxes_s, cnt_s, mat);
  k_scanfa<<<NP, 64, 0, stream>>>(mat, cnt_s, scores_s, fa, C, mb);
  k_fb<<<B, 1024, 0, stream>>>(fa, boxes_s, (float*)d_out, B, C, mb);
}

// Round 19
// 349.556 us; speedup vs baseline: 1.0814x; 1.0814x over previous
//
#include <hip/hip_runtime.h>
#include <hip/hip_bf16.h>

typedef unsigned long long u64;

#define KNMS 1000      // MAX_BOX_PRE_NMS (hardcoded in reference)
#define KP   1024      // padded stride for per-pair arrays
#define CAP  4096      // candidate capacity per pair
#define NBIN 8192      // radix-select histogram bins (score bits >> 18)
#define SLICES 320     // k_selA: A-dim slices per batch (= 64*5)
#define SCAP 32        // per (slice,class) key capacity (mean ~10, +7 sigma)
#define SLOTS (SLICES*SCAP)
#define CMAX 128       // fast-select supports C <= CMAX (else fallback path)
#define FSEL 1024      // k_fb compacted-candidate capacity
#define IOU_THR 0.5f

#define NEGINF __uint_as_float(0xFF800000u)

// ---------------------------------------------------------------------------
// helpers
// ---------------------------------------------------------------------------

__device__ __forceinline__ void find_cutoff(unsigned int* hist, int nbins,
    unsigned int* csum, int nthreads, int tid, unsigned int rank,
    unsigned int* s_bin, unsigned int* s_gt, unsigned int* s_total, int* s_all) {
  int chunk = nbins / nthreads;
  unsigned int cs = 0;
  int base = tid * chunk;
  for (int q = 0; q < chunk; q++) cs += hist[base + q];
  csum[tid] = cs;
  __syncthreads();
  if (tid == 0) {
    unsigned int total = 0;
    for (int ch = 0; ch < nthreads; ch++) total += csum[ch];
    *s_total = total;
    if (total <= rank) { *s_bin = 0u; *s_gt = 0u; *s_all = 1; }
    else {
      unsigned int acc = 0; int ch = nthreads - 1;
      while (acc + csum[ch] < rank) { acc += csum[ch]; ch--; }
      int bin = ch * chunk + chunk - 1;
      while (acc + hist[bin] < rank) { acc += hist[bin]; bin--; }
      *s_bin = (unsigned)bin; *s_gt = acc; *s_all = 0;
    }
  }
  __syncthreads();
}

template<int N, int NT>
__device__ __forceinline__ void bitonic_desc(u64* a, int tid) {
  for (int k = 2; k <= N; k <<= 1) {
    for (int j = k >> 1; j > 0; j >>= 1) {
      for (int t = tid; t < N; t += NT) {
        int ixj = t ^ j;
        if (ixj > t) {
          u64 x = a[t], y = a[ixj];
          if (((t & k) == 0) ? (x < y) : (x > y)) { a[t] = y; a[ixj] = x; }
        }
      }
      __syncthreads();
    }
  }
}

__device__ __forceinline__ u64 shflx64(u64 v, int m) {
  unsigned lo = (unsigned)v, hi = (unsigned)(v >> 32);
  lo = (unsigned)__shfl_xor((int)lo, m);
  hi = (unsigned)__shfl_xor((int)hi, m);
  return ((u64)hi << 32) | (u64)lo;
}

// Hybrid register/LDS bitonic sort of exactly 1024 u64 keys, descending.
// Requires blockDim.x == 1024; element tid lives in a register. Substages
// with j<64 are wave-local __shfl_xor (NO barrier, 45 of 55); only j>=64
// round-trips LDS (10 substages, 20 barriers). Same comparison network as
// bitonic_desc -> identical result (keys unique).
__device__ __forceinline__ void bitonic1024_hybrid(u64* a, int tid) {
  u64 v = a[tid];
  for (int k = 2; k <= 1024; k <<= 1) {
    for (int j = k >> 1; j > 0; j >>= 1) {
      u64 p;
      if (j >= 64) {
        __syncthreads();
        a[tid] = v;
        __syncthreads();
        p = a[tid ^ j];
      } else {
        p = shflx64(v, j);
      }
      bool dirdesc = ((tid & k) == 0);        // k=1024: true for all tid<1024
      bool lower = ((tid & j) == 0);
      u64 mx = v > p ? v : p;
      u64 mn = v > p ? p : v;
      v = (dirdesc == lower) ? mx : mn;
    }
  }
  __syncthreads();
  a[tid] = v;
  __syncthreads();
}

// Bit-exact greedy-NMS predicate vs reference, PURE f32 (Sterbenz argument,
// see round-6 notes): fl(I/U) > 0.5  <=>  (I+I) - U > U * 2^-24  in f32.
__device__ __forceinline__ bool iou_gt(float4 bi, float ai, float4 bj, float aj) {
  float ltx = fmaxf(bi.x, bj.x), lty = fmaxf(bi.y, bj.y);
  float rbx = fminf(bi.z, bj.z), rby = fminf(bi.w, bj.w);
  float ww = fmaxf(rbx - ltx, 0.f), hh = fmaxf(rby - lty, 0.f);
  float inter = ww * hh;
  float uni = (ai + aj) - inter;
  float q = (inter + inter) - uni;
  float t = uni * 0x1p-24f;
  return q > t;
}

// ---------------------------------------------------------------------------
// kernel S0: per batch, sample 4096 anchor-rows, build per-class 64-bin hists
// relative to thr's coarse bin, emit per-pair bit-cutoff AND a fused float
// GATE (see round-10 notes). Also zeroes gflag.
// ---------------------------------------------------------------------------
__global__ __launch_bounds__(1024) void k_sample(const float* __restrict__ cls,
    const float* __restrict__ thr_p, unsigned* __restrict__ gcut,
    float* __restrict__ gatef, unsigned* __restrict__ gflag, int A, int C) {
  int b = blockIdx.x, tid = threadIdx.x;
  __shared__ unsigned hist[CMAX * 64];
  float thr = *thr_p;
  unsigned base_bin = __float_as_uint(thr) >> 18;
  for (int i = tid; i < C * 64; i += 1024) hist[i] = 0u;
  __syncthreads();
  const float* src = cls + (size_t)b * A * C;
  const int NS = 4096;
  if ((C & 3) == 0) {
    int C4 = C >> 2;
    const float4* s4 = (const float4*)src;
    int tot4 = NS * C4;
    for (int idx = tid; idx < tot4; idx += 1024) {
      int s = idx / C4, c4 = idx - s * C4;
      int a = (int)(((long long)s * A) >> 12);
      float4 v = s4[(size_t)a * C4 + c4];
      float vv[4] = {v.x, v.y, v.z, v.w};
#pragma unroll
      for (int q = 0; q < 4; q++) {
        float sv = vv[q];
        if (sv > thr) {
          unsigned rel = (__float_as_uint(sv) >> 18) - base_bin;
          if (rel > 63u) rel = 63u;
          atomicAdd(&hist[(c4 * 4 + q) * 64 + rel], 1u);
        }
      }
    }
  } else {
    int tot = NS * C;
    for (int idx = tid; idx < tot; idx += 1024) {
      int s = idx / C, c = idx - s * C;
      int a = (int)(((long long)s * A) >> 12);
      float sv = src[(size_t)a * C + c];
      if (sv > thr) {
        unsigned rel = (__float_as_uint(sv) >> 18) - base_bin;
        if (rel > 63u) rel = 63u;
        atomicAdd(&hist[c * 64 + rel], 1u);
      }
    }
  }
  __syncthreads();
  if (tid < C) {
    int ns = NS < A ? NS : A;
    long long r = (1500LL * ns) / A; if (r < 1) r = 1;
    unsigned acc = 0; int bin = -1;
    for (int rb = 63; rb >= 0; --rb) {
      acc += hist[tid * 64 + rb];
      if (acc >= (unsigned)r) { bin = rb; break; }
    }
    unsigned cutv = (bin < 0) ? 0u : (base_bin + (unsigned)bin);
    gcut[b * C + tid] = cutv;
    float gate = thr;
    if (cutv != 0u) {
      unsigned cb = cutv << 18;
      if (__uint_as_float(cb) > thr) gate = __uint_as_float(cb - 1u);
    }
    gatef[b * C + tid] = gate;
    gflag[b * C + tid] = 0u;
  }
}

// ---------------------------------------------------------------------------
// kernel S1 (vec, C%4==0): divide-free streaming compact (round-10 version).
// ---------------------------------------------------------------------------
__global__ void k_selA(const float* __restrict__ cls,
    const float* __restrict__ gatef, u64* __restrict__ gcand,
    unsigned* __restrict__ gpc, unsigned* __restrict__ gflag, int A, int C) {
  int slice = blockIdx.x, b = blockIdx.y, tid = threadIdx.x;
  int nt = blockDim.x;
  __shared__ u64 stage[CMAX * SCAP];
  __shared__ unsigned pcnt[CMAX];
  int C4 = C >> 2;
  for (int i = tid; i < C; i += nt) pcnt[i] = 0u;
  __syncthreads();
  int ANC = (A + SLICES - 1) / SLICES;
  int a0 = slice * ANC, a1 = min(A, a0 + ANC);
  int c4 = tid % C4;
  int r0 = tid / C4;
  int R = nt / C4;
  float4 g4 = ((const float4*)(gatef + (size_t)b * C))[c4];
  const float4* p = (const float4*)cls + (size_t)b * A * C4
                    + (size_t)(a0 + r0) * C4 + c4;
  int cb = c4 << 2;
  for (int ar = a0 + r0; ar < a1; ar += R, p += (size_t)R * C4) {
    float4 v = *p;
    bool p0 = v.x > g4.x, p1 = v.y > g4.y, p2 = v.z > g4.z, p3 = v.w > g4.w;
    if (p0 | p1 | p2 | p3) {
      unsigned ia = (unsigned)(~(unsigned)ar);
      if (p0) { unsigned pos = atomicAdd(&pcnt[cb + 0], 1u);
        if (pos < SCAP) stage[(cb + 0) * SCAP + pos] = ((u64)__float_as_uint(v.x) << 32) | ia; }
      if (p1) { unsigned pos = atomicAdd(&pcnt[cb + 1], 1u);
        if (pos < SCAP) stage[(cb + 1) * SCAP + pos] = ((u64)__float_as_uint(v.y) << 32) | ia; }
      if (p2) { unsigned pos = atomicAdd(&pcnt[cb + 2], 1u);
        if (pos < SCAP) stage[(cb + 2) * SCAP + pos] = ((u64)__float_as_uint(v.z) << 32) | ia; }
      if (p3) { unsigned pos = atomicAdd(&pcnt[cb + 3], 1u);
        if (pos < SCAP) stage[(cb + 3) * SCAP + pos] = ((u64)__float_as_uint(v.w) << 32) | ia; }
    }
  }
  __syncthreads();
  for (int idx = tid; idx < C * SCAP; idx += nt) {
    int c = idx >> 5, j = idx & (SCAP - 1);
    unsigned cnt2 = pcnt[c]; if (cnt2 > SCAP) cnt2 = SCAP;
    if ((unsigned)j < cnt2)
      gcand[(size_t)(b * C + c) * SLOTS + slice * SCAP + j] = stage[idx];
  }
  for (int c = tid; c < C; c += nt) {
    unsigned cnt2 = pcnt[c];
    if (cnt2 > SCAP) { atomicOr(&gflag[b * C + c], 1u); cnt2 = SCAP; }
    gpc[(size_t)(b * C + c) * SLICES + slice] = cnt2;
  }
}

// Scalar variant for C % 4 != 0.
__global__ void k_selAs(const float* __restrict__ cls,
    const float* __restrict__ gatef, u64* __restrict__ gcand,
    unsigned* __restrict__ gpc, unsigned* __restrict__ gflag, int A, int C) {
  int slice = blockIdx.x, b = blockIdx.y, tid = threadIdx.x;
  int nt = blockDim.x;
  __shared__ u64 stage[CMAX * SCAP];
  __shared__ unsigned pcnt[CMAX];
  for (int i = tid; i < C; i += nt) pcnt[i] = 0u;
  __syncthreads();
  int ANC = (A + SLICES - 1) / SLICES;
  int a0 = slice * ANC, a1 = min(A, a0 + ANC);
  int c = tid % C;
  int r0 = tid / C;
  int R = nt / C;
  float gate = gatef[(size_t)b * C + c];
  const float* p = cls + (size_t)b * A * C + (size_t)(a0 + r0) * C + c;
  for (int ar = a0 + r0; ar < a1; ar += R, p += (size_t)R * C) {
    float sv = *p;
    if (sv > gate) {
      unsigned pos = atomicAdd(&pcnt[c], 1u);
      if (pos < SCAP)
        stage[c * SCAP + pos] = ((u64)__float_as_uint(sv) << 32) | (unsigned)(~(unsigned)ar);
    }
  }
  __syncthreads();
  for (int idx = tid; idx < C * SCAP; idx += nt) {
    int cc = idx >> 5, j = idx & (SCAP - 1);
    unsigned cnt2 = pcnt[cc]; if (cnt2 > SCAP) cnt2 = SCAP;
    if ((unsigned)j < cnt2)
      gcand[(size_t)(b * C + cc) * SLOTS + slice * SCAP + j] = stage[idx];
  }
  for (int cc = tid; cc < C; cc += nt) {
    unsigned cnt2 = pcnt[cc];
    if (cnt2 > SCAP) { atomicOr(&gflag[b * C + cc], 1u); cnt2 = SCAP; }
    gpc[(size_t)(b * C + cc) * SLICES + slice] = cnt2;
  }
}

// ---------------------------------------------------------------------------
// kernel S2: per pair: WAVE-SCAN slice counts (2 barriers, was 36), gather,
// radix-select top <=1024, HYBRID register bitonic-1024 (20 barriers, was
// 55). Full bitonic-4096 fallback unchanged (rare). Round-19: r18 counters
// showed selB = 85us at VALUBusy 7.5% -- pure barrier latency.
// ---------------------------------------------------------------------------
__global__ __launch_bounds__(1024) void k_selB(const u64* __restrict__ gcand,
    const unsigned* __restrict__ gpc, const unsigned* __restrict__ gcut,
    const unsigned* __restrict__ gflag, const float* __restrict__ gatef,
    const float* __restrict__ cls, const float* __restrict__ thr_p,
    const float* __restrict__ tanch,
    float* __restrict__ scores_s, float* __restrict__ boxes_s,
    int* __restrict__ cnt_s, int A, int C) {
  int pair = blockIdx.x, tid = threadIdx.x;
  int b = pair / C, c = pair - b * C;
  __shared__ union { unsigned hist[NBIN]; u64 cand[CAP]; } sh;  // 32KB
  __shared__ u64 cand2[1024];                                   // 8KB
  __shared__ unsigned h2[2048];                                 // 8KB
  __shared__ unsigned hw[16][64];                               // 4KB
  __shared__ unsigned hist64[64];
  __shared__ unsigned cnts[SLICES];
  __shared__ unsigned pre[SLICES];   // EXCLUSIVE per-slice prefix
  __shared__ unsigned csum[1024];
  __shared__ unsigned s_b1, s_gt, s_tot, s_b2, s_gt2, s_tot2;
  __shared__ int s_all, s_all2, s_ovf, s_mode, s_lvl2, s_wide, s_ntake;

  unsigned flag = gflag[pair];
  for (int i = tid; i < SLICES; i += 1024)
    cnts[i] = gpc[(size_t)pair * SLICES + i];
  __syncthreads();
  // wave-0 scan: 5 slices/lane (SLICES = 64*5), shfl_up across 64 lanes
  if (tid < 64) {
    unsigned loc[5]; unsigned s = 0;
#pragma unroll
    for (int q = 0; q < 5; q++) { loc[q] = cnts[tid * 5 + q]; s += loc[q]; }
    unsigned inc = s;
    for (int d = 1; d < 64; d <<= 1) {
      unsigned o = __shfl_up(inc, d);
      if (tid >= d) inc += o;
    }
    unsigned run = inc - s;                    // group-exclusive
#pragma unroll
    for (int q = 0; q < 5; q++) { pre[tid * 5 + q] = run; run += loc[q]; }
    if (tid == 63) s_tot = run;                // grand total
  }
  __syncthreads();
  unsigned total = s_tot;
  bool mode_sampled = (gcut[pair] != 0u);
  bool bad = (flag != 0u) || (total > CAP) ||
             (mode_sampled && total < (unsigned)KNMS);
  unsigned n_valid_u;
  bool fullsort;
  if (!bad) {
    for (int t = tid; t < CAP; t += 1024) sh.cand[t] = 0ull;
    __syncthreads();
    const u64* src = gcand + (size_t)pair * SLOTS;
    for (int idx = tid; idx < SLOTS; idx += 1024) {
      int s = idx >> 5, j = idx & (SCAP - 1);
      if ((unsigned)j < cnts[s]) sh.cand[pre[s] + j] = src[idx];
    }
    n_valid_u = total < (unsigned)KNMS ? total : (unsigned)KNMS;
    // ---- radix-select top <=1024 ----
    unsigned base = __float_as_uint(gatef[pair]) >> 18;
    for (int i = tid; i < 16 * 64; i += 1024) (&hw[0][0])[i] = 0u;
    if (tid == 0) { s_wide = 0; s_ntake = 0; }
    __syncthreads();
    int wv = tid >> 6;
    for (int t = tid; t < CAP; t += 1024) {
      u64 key = sh.cand[t];
      if (!key) continue;
      unsigned rel = ((unsigned)(key >> 32) >> 18) - base;
      if (rel > 63u) s_wide = 1;
      else atomicAdd(&hw[wv][rel], 1u);
    }
    __syncthreads();
    if (tid < 64) {
      unsigned s = 0;
#pragma unroll
      for (int w = 0; w < 16; w++) s += hw[w][tid];
      hist64[tid] = s;
    }
    __syncthreads();
    if (tid == 0) {
      int mode = 0; unsigned b1 = 0, gt = 0; int lvl2 = 0;
      if (s_wide) mode = 2;
      else if (total > (unsigned)KNMS) {
        unsigned acc = 0; int bin = 63;
        for (; bin > 0; --bin) {
          unsigned h = hist64[bin];
          if (acc + h >= (unsigned)KNMS) break;
          acc += h;
        }
        b1 = (unsigned)bin; gt = acc;
        if (gt + hist64[b1] > 1024u) lvl2 = 1;
      }
      s_b1 = b1; s_gt = gt; s_mode = mode; s_lvl2 = lvl2;
    }
    __syncthreads();
    unsigned b1v = s_b1, gtv = s_gt;
    int lvl2 = s_lvl2;
    unsigned b2v = 0;
    if (s_mode == 0 && lvl2) {
      for (int i = tid; i < 2048; i += 1024) h2[i] = 0u;
      __syncthreads();
      for (int t = tid; t < CAP; t += 1024) {
        u64 key = sh.cand[t];
        if (!key) continue;
        unsigned bits = (unsigned)(key >> 32);
        if (((bits >> 18) - base) == b1v)
          atomicAdd(&h2[(bits >> 7) & 2047u], 1u);
      }
      __syncthreads();
      find_cutoff(h2, 2048, csum, 1024, tid, (unsigned)KNMS - gtv,
                  &s_b2, &s_gt2, &s_tot2, &s_all2);
      if (tid == 0) {
        if (s_all2 || gtv + s_gt2 + h2[s_b2] > 1024u) s_mode = 2; // paranoid
      }
      __syncthreads();
      b2v = s_all2 ? 0u : s_b2;
    }
    fullsort = (s_mode == 2);
    if (!fullsort) {
      cand2[tid] = 0ull;
      __syncthreads();
      for (int t = tid; t < CAP; t += 1024) {
        u64 key = sh.cand[t];
        if (!key) continue;
        unsigned bits = (unsigned)(key >> 32);
        unsigned rel = (bits >> 18) - base;
        bool take = rel > b1v ||
                    (rel == b1v && (!lvl2 || ((bits >> 7) & 2047u) >= b2v));
        if (take) {
          int pos = atomicAdd(&s_ntake, 1);
          if (pos < 1024) cand2[pos] = key;
        }
      }
      __syncthreads();
    }
  } else {
    // ---- exact fallback (strided reads; rare) ----
    fullsort = true;
    const float* col = cls + (size_t)b * A * C + c;
    float thr = *thr_p;
    for (int i = tid; i < NBIN; i += 1024) sh.hist[i] = 0u;
    __syncthreads();
    for (int a = tid; a < A; a += 1024) {
      float sv = col[(size_t)a * C];
      if (sv > thr) atomicAdd(&sh.hist[__float_as_uint(sv) >> 18], 1u);
    }
    __syncthreads();
    find_cutoff(sh.hist, NBIN, csum, 1024, tid, KNMS, &s_b1, &s_gt, &s_tot, &s_all);
    unsigned b1 = s_all ? 0u : s_b1;
    unsigned tot = s_tot;
    __syncthreads();
    for (int t = tid; t < CAP; t += 1024) sh.cand[t] = 0ull;
    if (tid == 0) s_ovf = 0;
    __syncthreads();
    int lane = tid & 63, wv = tid >> 6;     // 16 waves, SEG=240, OVF=256
    u64* seg = sh.cand + wv * 240;
    int nloc = 0;
    u64 lmask = (1ull << lane) - 1ull;
    for (int a = tid; a < A; a += 1024) {
      float sv = col[(size_t)a * C];
      unsigned bits = __float_as_uint(sv);
      bool take = (sv > thr) && ((bits >> 18) >= b1);
      u64 m = __ballot(take);
      if (m) {
        if (take) {
          u64 key = ((u64)bits << 32) | (unsigned)(~(unsigned)a);
          int pos = nloc + (int)__popcll(m & lmask);
          if (pos < 240) seg[pos] = key;
          else { int p2 = atomicAdd(&s_ovf, 1); if (p2 < 256) sh.cand[16 * 240 + p2] = key; }
        }
        nloc += (int)__popcll(m);
      }
    }
    __syncthreads();
    n_valid_u = tot < (unsigned)KNMS ? tot : (unsigned)KNMS;
  }

  if (fullsort) bitonic_desc<CAP, 1024>(sh.cand, tid);
  else          bitonic1024_hybrid(cand2, tid);
  const u64* osrc = fullsort ? (const u64*)sh.cand : (const u64*)cand2;

  int n_valid = (int)n_valid_u;
  for (int k = tid; k < KNMS; k += 1024) {
    u64 key = osrc[k];
    float sc; float4 bx;
    if (k < n_valid && key != 0ull) {
      sc = __uint_as_float((unsigned)(key >> 32));
      unsigned a = ~(unsigned)key;
      bx = ((const float4*)tanch)[(size_t)b * A + a];
    } else {
      sc = NEGINF; bx = make_float4(0.f, 0.f, 0.f, 0.f);
    }
    scores_s[(size_t)pair * KP + k] = sc;
    ((float4*)boxes_s)[(size_t)pair * KP + k] = bx;
  }
  if (tid == 0) cnt_s[pair] = n_valid;
}

// ---------------------------------------------------------------------------
// kernel 3: suppressor-COLUMN matrix colm[pair][wi][j] (round-14 internals,
// 115us proven). Round-19: merged back to ONE dispatch (reclaims the ~27us
// split tax; visibility purpose served). Block (pair,g) owns i-chunks
// {Ac=g, Bc=15-g} (balanced).
// ---------------------------------------------------------------------------
__global__ __launch_bounds__(256) void k_iou(const float* __restrict__ boxes_s,
    const int* __restrict__ cnt_s, u64* __restrict__ mat) {
  int pair = blockIdx.x, g = blockIdx.y;   // g in [0,8)
  int Ac = g, Bc = 15 - g;
  int cnt = cnt_s[pair];
  __shared__ float4 sbox[KNMS];
  __shared__ u64 rowm[2][KP];
  for (int i = threadIdx.x; i < KNMS; i += 256)
    sbox[i] = ((const float4*)boxes_s)[(size_t)pair * KP + i];
  {
    u64* rz = &rowm[0][0];
    for (int i = threadIdx.x; i < 2 * KP; i += 256) rz[i] = 0ull;
  }
  __syncthreads();
  int lane = threadIdx.x & 63;
  int wv = __builtin_amdgcn_readfirstlane(threadIdx.x >> 6);
  float4 z4 = make_float4(0.f, 0.f, 0.f, 0.f);
  float4 biA = sbox[Ac * 64 + lane];
  int ib = Bc * 64 + lane;
  float4 biB = (ib < KNMS) ? sbox[ib] : z4;
  float aiA = (biA.z - biA.x) * (biA.w - biA.y);
  float aiB = (biB.z - biB.x) * (biB.w - biB.y);
  int lim = cnt;
  // seg1: j in (Ac*64, Ac*64+64): A masked (lanes < j-Ac*64)
  int e1 = Ac * 64 + 64; if (e1 > lim) e1 = lim;
  for (int j = Ac * 64 + 1 + wv; j < e1; j += 4) {
    float4 bj = sbox[j];
    float aj = (bj.z - bj.x) * (bj.w - bj.y);
    u64 mk = (1ull << (j - Ac * 64)) - 1ull;
    u64 w0 = __ballot(iou_gt(biA, aiA, bj, aj)) & mk;
    if (lane == 0) rowm[0][j] = w0;
  }
  // seg2: j in [Ac*64+64, Bc*64]: A plain (unroll-2 per wave)
  int s2e = Bc * 64 + 1; if (s2e > lim) s2e = lim;
  for (int j = Ac * 64 + 64 + (wv << 1); j < s2e; j += 8) {
    float4 bj0 = sbox[j];
    bool h2b = (j + 1 < s2e);
    float4 bj1 = h2b ? sbox[j + 1] : z4;
    float aj0 = (bj0.z - bj0.x) * (bj0.w - bj0.y);
    float aj1 = (bj1.z - bj1.x) * (bj1.w - bj1.y);
    u64 w00 = __ballot(iou_gt(biA, aiA, bj0, aj0));
    u64 w01 = __ballot(iou_gt(biA, aiA, bj1, aj1));
    if (lane == 0) { rowm[0][j] = w00; if (h2b) rowm[0][j + 1] = w01; }
  }
  // seg3: j in (Bc*64, Bc*64+64): A plain + B masked
  int e3 = Bc * 64 + 64; if (e3 > lim) e3 = lim;
  for (int j = Bc * 64 + 1 + wv; j < e3; j += 4) {
    float4 bj = sbox[j];
    float aj = (bj.z - bj.x) * (bj.w - bj.y);
    u64 w0 = __ballot(iou_gt(biA, aiA, bj, aj));
    u64 mk = (1ull << (j - Bc * 64)) - 1ull;
    u64 w1 = __ballot(iou_gt(biB, aiB, bj, aj)) & mk;
    if (lane == 0) { rowm[0][j] = w0; rowm[1][j] = w1; }
  }
  // seg4: j in [Bc*64+64, lim): A plain + B plain (unroll-2 per wave)
  for (int j = Bc * 64 + 64 + (wv << 1); j < lim; j += 8) {
    float4 bj0 = sbox[j];
    bool h2b = (j + 1 < lim);
    float4 bj1 = h2b ? sbox[j + 1] : z4;
    float aj0 = (bj0.z - bj0.x) * (bj0.w - bj0.y);
    float aj1 = (bj1.z - bj1.x) * (bj1.w - bj1.y);
    u64 w00 = __ballot(iou_gt(biA, aiA, bj0, aj0));
    u64 w10 = __ballot(iou_gt(biB, aiB, bj0, aj0));
    u64 w01 = __ballot(iou_gt(biA, aiA, bj1, aj1));
    u64 w11 = __ballot(iou_gt(biB, aiB, bj1, aj1));
    if (lane == 0) {
      rowm[0][j] = w00; rowm[1][j] = w10;
      if (h2b) { rowm[0][j + 1] = w01; rowm[1][j + 1] = w11; }
    }
  }
  __syncthreads();
  {
    u64* dstA = mat + ((size_t)pair * 16 + Ac) * KP;
    for (int t = Ac * 64 + threadIdx.x; t < cnt; t += 256) dstA[t] = rowm[0][t];
    u64* dstB = mat + ((size_t)pair * 16 + Bc) * KP;
    for (int t = Bc * 64 + threadIdx.x; t < cnt; t += 256) dstB[t] = rowm[1][t];
  }
}

// ---------------------------------------------------------------------------
// kernel 4 (scan+fa, colm orientation; round-14 version): 1 wave per pair.
// key = (score_bits << 32) | ~(c*KNMS + k)
// ---------------------------------------------------------------------------
__global__ __launch_bounds__(64) void k_scanfa(const u64* __restrict__ mat,
    const int* __restrict__ cnt_s, const float* __restrict__ scores_s,
    u64* __restrict__ fa, int C, int mb) {
  int pair = blockIdx.x;
  int l = threadIdx.x;
  int cnt = cnt_s[pair];
  const u64* cm = mat + (size_t)pair * KP * 16;
  u64 supw = 0ull;
  u64 kfin = 0ull;
  for (int t = 0; t < 16; t++) {
    int base = t * 64;
    if (base >= cnt) break;
    int nb = cnt - base; if (nb > 64) nb = 64;
    u64 validt = (nb >= 64) ? ~0ull : ((1ull << nb) - 1ull);
    const u64* cmt = cm + (size_t)t * KP;
    u64 dg = cmt[base + l];
    u64 v[15];
#pragma unroll
    for (int q = 0; q < 15; q++) {
      int jw = t + 1 + q;
      v[q] = (jw < 16 && jw * 64 < cnt) ? cmt[jw * 64 + l] : 0ull;
    }
    u64 supt = __shfl(supw, t);
    u64 rem = validt & ~supt;
    u64 nz = __ballot(dg != 0ull) & rem;
    u64 keep = rem & ~nz;
    while (nz) {
      int i = __ffsll((long long)nz) - 1;
      nz &= nz - 1;
      u64 di = __shfl(dg, i);
      if ((di & keep) == 0ull) keep |= 1ull << i;
    }
    if (l == t) kfin = keep;
#pragma unroll
    for (int q = 0; q < 15; q++) {
      int jw = t + 1 + q;
      if (jw < 16) {
        u64 bal = __ballot((v[q] & keep) != 0ull);
        if (l == jw) supw |= bal;
      }
    }
  }
  int c = pair % C;
  int pc = __popcll(kfin);
  int scan = pc;
  for (int d = 1; d < 16; d <<= 1) {
    int o = __shfl_up(scan, d);
    if (l >= d) scan += o;
  }
  int basep = scan - pc;
  int total = __shfl(scan, 15);
  if (l < 16) {
    u64 mm = kfin; int r = basep;
    while (mm && r < mb) {
      int bit = __ffsll((long long)mm) - 1; mm &= mm - 1;
      int k = l * 64 + bit;
      float s = scores_s[(size_t)pair * KP + k];
      fa[(size_t)pair * mb + r] =
          ((u64)__float_as_uint(s) << 32) | (unsigned)(~(unsigned)(c * KNMS + k));
      r++;
    }
  }
  int start = total < mb ? total : mb;
  for (int r = start + l; r < mb; r += 64) fa[(size_t)pair * mb + r] = 0ull;
}

// ---------------------------------------------------------------------------
// kernel 5b: per batch: top-mb of C*mb keys via 2-level radix select +
// HYBRID register bitonic-1024.
// ---------------------------------------------------------------------------
__global__ __launch_bounds__(1024) void k_fb(const u64* __restrict__ fa,
    const float* __restrict__ boxes_s, float* __restrict__ out,
    int B, int C, int mb) {
  int b = blockIdx.x, tid = threadIdx.x;
  __shared__ union { unsigned int hist[NBIN]; u64 cand[FSEL]; } sh;
  __shared__ unsigned int csum[1024];
  __shared__ unsigned int s_b1, s_gt, s_tot, s_b2, s_gt2, s_tot2;
  __shared__ int s_all, s_all2, s_n, s_lvl2;
  int nk = C * mb;
  const u64* src = fa + (size_t)b * nk;

  for (int i = tid; i < NBIN; i += 1024) sh.hist[i] = 0u;
  __syncthreads();
  for (int i = tid; i < nk; i += 1024) {
    u64 key = src[i];
    if (key) atomicAdd(&sh.hist[(unsigned)(key >> 32) >> 18], 1u);
  }
  __syncthreads();
  find_cutoff(sh.hist, NBIN, csum, 1024, tid, (unsigned)mb, &s_b1, &s_gt, &s_tot, &s_all);
  unsigned b1 = s_all ? 0u : s_b1;
  unsigned gt1 = s_gt, tot = s_tot;
  int all1 = s_all;
  unsigned m1 = sh.hist[b1];
  if (tid == 0) s_lvl2 = (!all1 && gt1 + m1 > FSEL) ? 1 : 0;
  __syncthreads();
  int lvl2 = s_lvl2;
  unsigned b2 = 0; int all2 = 1;
  if (lvl2) {
    for (int i = tid; i < 2048; i += 1024) sh.hist[i] = 0u;
    __syncthreads();
    for (int i = tid; i < nk; i += 1024) {
      u64 key = src[i];
      if (key) {
        unsigned bits = (unsigned)(key >> 32);
        if ((bits >> 18) == b1) atomicAdd(&sh.hist[(bits >> 7) & 2047u], 1u);
      }
    }
    __syncthreads();
    find_cutoff(sh.hist, 2048, csum, 1024, tid, (unsigned)mb - gt1,
                &s_b2, &s_gt2, &s_tot2, &s_all2);
    all2 = s_all2;
    b2 = all2 ? 0u : s_b2;
  }
  for (int t = tid; t < FSEL; t += 1024) sh.cand[t] = 0ull;
  if (tid == 0) s_n = 0;
  __syncthreads();
  for (int i = tid; i < nk; i += 1024) {
    u64 key = src[i];
    if (!key) continue;
    unsigned bits = (unsigned)(key >> 32);
    unsigned bin = bits >> 18;
    bool take = all1 || bin > b1 ||
                (bin == b1 && (!lvl2 || all2 || ((bits >> 7) & 2047u) >= b2));
    if (take) {
      int pos = atomicAdd(&s_n, 1);
      if (pos < FSEL) sh.cand[pos] = key;
    }
  }
  __syncthreads();
  bitonic1024_hybrid(sh.cand, tid);

  int n_out = (int)tot < mb ? (int)tot : mb;
  for (int k = tid; k < mb; k += 1024) {
    u64 key = sh.cand[k];
    float4 bx = make_float4(0.f, 0.f, 0.f, 0.f);
    float sc = 0.f, cf = -1.f;
    if (k < n_out && key != 0ull) {
      sc = __uint_as_float((unsigned)(key >> 32));
      unsigned flat = ~(unsigned)key;
      int c = flat / KNMS;
      int kk = flat - c * KNMS;
      bx = ((const float4*)boxes_s)[(size_t)(b * C + c) * KP + kk];
      cf = (float)c;
    }
    size_t ro = (size_t)(b * mb + k) * 4;
    out[ro + 0] = bx.x; out[ro + 1] = bx.y; out[ro + 2] = bx.z; out[ro + 3] = bx.w;
    out[(size_t)B * mb * 4 + b * mb + k] = sc;
    out[(size_t)B * mb * 5 + b * mb + k] = cf;
  }
}

// ---------------------------------------------------------------------------
extern "C" void kernel_launch(void* const* d_in, const int* in_sizes, int n_in,
                              void* d_out, int out_size, void* d_ws, size_t ws_size,
                              hipStream_t stream) {
  const float* classification = (const float*)d_in[3];
  const float* tanch = (const float*)d_in[4];
  const float* thr_p = (const float*)d_in[5];

  int B = in_sizes[0] / (3 * 64 * 64);
  if (B <= 0) B = 4;
  long long BA = (long long)in_sizes[4] / 4;
  int A = (int)(BA / B);
  int C = (int)((long long)in_sizes[3] / BA);
  int NP = B * C;
  int mb = out_size / (B * 6);

  auto rsz = [](size_t x) { return (x + 255) & ~(size_t)255; };
  size_t off = 0;
  auto take = [&](size_t bytes) {
    void* p = (char*)d_ws + off;
    off += rsz(bytes);
    return p;
  };
  float* scores_s = (float*)take((size_t)NP * KP * 4);
  float* boxes_s  = (float*)take((size_t)NP * KP * 16);
  float* area_s   = (float*)take((size_t)NP * KP * 4);   // only used as fa
  int*   cnt_s    = (int*)take((size_t)NP * 4);
  u64*   mat      = (u64*)take((size_t)NP * KP * 16 * 8);  // 41.9 MB (colm)

  // Aliases (disjoint lifetimes):
  //   gcand/gpc/gcut/gflag/gatef live k_sample..k_selB (before k_iou writes
  //   mat); fa aliases area_s (unused elsewhere; k_scanfa reads mat, so fa
  //   must not alias mat).
  char* matc = (char*)mat;
  size_t ao = 0;
  u64* gcand      = (u64*)(matc + ao);      ao += rsz((size_t)NP * SLOTS * 8);   // 26.2 MB
  unsigned* gpc   = (unsigned*)(matc + ao); ao += rsz((size_t)NP * SLICES * 4);  // 0.41 MB
  unsigned* gcut  = (unsigned*)(matc + ao); ao += rsz((size_t)NP * 4);
  unsigned* gflag = (unsigned*)(matc + ao); ao += rsz((size_t)NP * 4);
  float* gatef    = (float*)(matc + ao);    ao += rsz((size_t)NP * 4);
  u64* fa = (u64*)area_s;   // NP*mb*8 = 256 KB <= NP*KP*4 = 1.31 MB

  int fastsel = (C <= CMAX) ? 1 : 0;

  if (fastsel) {
    k_sample<<<B, 1024, 0, stream>>>(classification, thr_p, gcut, gatef, gflag, A, C);
    if ((C & 3) == 0) {
      int C4 = C >> 2;
      int R = 512 / C4; if (R < 1) R = 1;
      k_selA<<<dim3(SLICES, B), C4 * R, 0, stream>>>(classification, gatef,
                                                     gcand, gpc, gflag, A, C);
    } else {
      int R = 512 / C; if (R < 1) R = 1;
      k_selAs<<<dim3(SLICES, B), C * R, 0, stream>>>(classification, gatef,
                                                     gcand, gpc, gflag, A, C);
    }
  } else {
    hipMemsetAsync(gflag, 1, (size_t)NP * 4, stream);
    hipMemsetAsync(gcut, 0, (size_t)NP * 4, stream);
    hipMemsetAsync(gatef, 0, (size_t)NP * 4, stream);
  }
  k_selB<<<NP, 1024, 0, stream>>>(gcand, gpc, gcut, gflag, gatef, classification,
                                  thr_p, tanch, scores_s, boxes_s, cnt_s, A, C);
  k_iou<<<dim3(NP, 8), 256, 0, stream>>>(boxes_s, cnt_s, mat);
  k_scanfa<<<NP, 64, 0, stream>>>(mat, cnt_s, scores_s, fa, C, mb);
  k_fb<<<B, 1024, 0, stream>>>(fa, boxes_s, (float*)d_out, B, C, mb);
}